// Round 8
// baseline (79.574 us; speedup 1.0000x reference)
//
#include <hip/hip_runtime.h>
#include <math.h>

#define NB      8192
#define ND      2048
#define NC      100
#define NCP     112
#define ALPHA_  2.0f
#define MARGIN_ 0.05f

typedef short bf16x8 __attribute__((ext_vector_type(8)));
typedef float f32x4 __attribute__((ext_vector_type(4)));

static __device__ __forceinline__ unsigned short f2bf(float f) {
  unsigned u = __float_as_uint(f);
  u += 0x7FFFu + ((u >> 16) & 1u);
  return (unsigned short)(u >> 16);
}

// ---- prepW: Wtf fragment-major bf16: frag f=(ws*7+i)*64+l holds ------------
// W[ws*32+(l>>4)*8+j][i*16+(l&15)], j=0..7 (zero-pad col>=100)
__global__ __launch_bounds__(256) void k_prepW(const float* __restrict__ W,
                                               unsigned short* __restrict__ Wtf) {
  const int f   = blockIdx.x * 256 + threadIdx.x;  // 0..28671
  const int ws  = f / 448;
  const int rem = f - ws * 448;
  const int i   = rem >> 6;
  const int l   = rem & 63;
  const int col = i * 16 + (l & 15);
  const int k0  = ws * 32 + (l >> 4) * 8;
  bf16x8 v;
#pragma unroll
  for (int j = 0; j < 8; ++j)
    v[j] = (short)((col < NC) ? f2bf(W[(size_t)(k0 + j) * NC + col]) : 0);
  *(bf16x8*)(Wtf + (size_t)f * 8) = v;
}

// ---- prepG: G2 = W^T W, pa2 = A @ W (112x112 tiles via MFMA, no atomics) ---
__global__ __launch_bounds__(512) void k_prepG(const unsigned short* __restrict__ Wtf,
                                               const float* __restrict__ A,
                                               float* __restrict__ G2,
                                               float* __restrict__ pa2) {
  __shared__ float red[8][8][64];  // wave, val(4 G + 4 pa), lane
  const int t    = threadIdx.x;
  const int w    = t >> 6;
  const int lane = t & 63;
  const int ti   = blockIdx.x / 7;
  const int tj   = blockIdx.x % 7;
  const int arow = ti * 16 + (lane & 15);

  f32x4 accG = {0.f, 0.f, 0.f, 0.f};
  f32x4 accP = {0.f, 0.f, 0.f, 0.f};
#pragma unroll
  for (int s = 0; s < 8; ++s) {
    const int ws = w * 8 + s;
    const bf16x8 afr = *(const bf16x8*)(Wtf + (size_t)(ws * 7 + ti) * 512 + lane * 8);
    const bf16x8 bfr = *(const bf16x8*)(Wtf + (size_t)(ws * 7 + tj) * 512 + lane * 8);
    accG = __builtin_amdgcn_mfma_f32_16x16x32_bf16(afr, bfr, accG, 0, 0, 0);
    bf16x8 aa;
    if (arow < NC) {
      const float* __restrict__ ar =
          A + (size_t)arow * ND + ws * 32 + (lane >> 4) * 8;
      const float4 v0 = *(const float4*)(ar);
      const float4 v1 = *(const float4*)(ar + 4);
      aa[0] = (short)f2bf(v0.x); aa[1] = (short)f2bf(v0.y);
      aa[2] = (short)f2bf(v0.z); aa[3] = (short)f2bf(v0.w);
      aa[4] = (short)f2bf(v1.x); aa[5] = (short)f2bf(v1.y);
      aa[6] = (short)f2bf(v1.z); aa[7] = (short)f2bf(v1.w);
    } else {
#pragma unroll
      for (int q = 0; q < 8; ++q) aa[q] = 0;
    }
    accP = __builtin_amdgcn_mfma_f32_16x16x32_bf16(aa, bfr, accP, 0, 0, 0);
  }
#pragma unroll
  for (int rg = 0; rg < 4; ++rg) {
    red[w][rg][lane]     = accG[rg];
    red[w][4 + rg][lane] = accP[rg];
  }
  __syncthreads();
  if (w < 2) {
    const int vb = w * 4;  // 0: G, 4: pa
    float* __restrict__ dst = (w == 0) ? G2 : pa2;
#pragma unroll
    for (int rg = 0; rg < 4; ++rg) {
      float s = 0.f;
#pragma unroll
      for (int w2 = 0; w2 < 8; ++w2) s += red[w2][vb + rg][lane];
      const int row = ti * 16 + (lane >> 4) * 4 + rg;
      dst[row * NCP + tj * 16 + (lane & 15)] = s;
    }
  }
}

// ---- prep2: T=softmax(pa)-I ; Ut[cp][r] = (G T^T)[r][cp] -------------------
__global__ __launch_bounds__(128) void k_prep2(const float* __restrict__ G2,
                                               const float* __restrict__ pa2,
                                               float* __restrict__ Ut) {
  __shared__ float vals[128];
  __shared__ float tl[128];
  const int cp = blockIdx.x;
  const int t  = threadIdx.x;
  const float v = (t < NC) ? pa2[cp * NCP + t] : -INFINITY;
  vals[t] = v;
  __syncthreads();
  float m = -INFINITY;
  for (int c = 0; c < NC; ++c) m = fmaxf(m, vals[c]);
  float se = 0.f;
  for (int c = 0; c < NC; ++c) se += __expf(vals[c] - m);
  tl[t] = (t < NC) ? (__expf(v - m) / se - (t == cp ? 1.f : 0.f)) : 0.f;
  __syncthreads();
  if (t < NC) {
    float u = 0.f;
    for (int c = 0; c < NC; ++c) u = fmaf(G2[c * NCP + t], tl[c], u);
    Ut[cp * NC + t] = u;
  }
}

// ---- main: 16 waves x 128-K slices, per-wave LDS slab, atomic-free tail ----
__global__ __launch_bounds__(1024, 2) void k_main(const float* __restrict__ X,
                                                  const unsigned short* __restrict__ Wtf,
                                                  const int* __restrict__ Y,
                                                  const float* __restrict__ Ut,
                                                  float* __restrict__ S_part,
                                                  float* __restrict__ rowce,
                                                  float* __restrict__ rowap) {
  __shared__ __align__(16) char smem[65536];  // 16 x 4KB wave slabs; reused
  const int t    = threadIdx.x;
  const int w    = t >> 6;     // wave 0..15 = K-slice (128 K each)
  const int lane = t & 63;
  const int row0 = blockIdx.x * 16;
  char* __restrict__ wbase = smem + w * 4096;

  // ---- per-wave stage: 16 rows x 128 K, f32 -> bf16, XOR-swizzled [row][k] --
  {
    const int srow = lane >> 2;
    const int sc   = lane & 3;
    const float* __restrict__ xr =
        X + (size_t)(row0 + srow) * ND + w * 128 + sc * 8;
    const int wsz = (srow & 7) << 4;
#pragma unroll
    for (int j = 0; j < 4; ++j) {
      const float4 v0 = *(const float4*)(xr + j * 32);
      const float4 v1 = *(const float4*)(xr + j * 32 + 4);
      bf16x8 p;
      p[0] = (short)f2bf(v0.x); p[1] = (short)f2bf(v0.y);
      p[2] = (short)f2bf(v0.z); p[3] = (short)f2bf(v0.w);
      p[4] = (short)f2bf(v1.x); p[5] = (short)f2bf(v1.y);
      p[6] = (short)f2bf(v1.z); p[7] = (short)f2bf(v1.w);
      *(bf16x8*)(wbase + srow * 256 + ((sc * 16 + j * 64) ^ wsz)) = p;
    }
  }
  // no barrier: slab is wave-private (ds_write->ds_read ordered in-wave)

  const int r = lane & 15;
  const int g = lane >> 4;

  f32x4 acc[7];
  const f32x4 z = {0.f, 0.f, 0.f, 0.f};
#pragma unroll
  for (int i = 0; i < 7; ++i) acc[i] = z;

  const char* __restrict__ abase = wbase + r * 256;
  const int asz = (r & 7) << 4;
#pragma unroll
  for (int s = 0; s < 4; ++s) {
    const bf16x8 xf = *(const bf16x8*)(abase + ((s * 64 + g * 16) ^ asz));
    const unsigned short* __restrict__ bp =
        Wtf + (size_t)((w * 4 + s) * 7) * 512 + lane * 8;
#pragma unroll
    for (int i = 0; i < 7; ++i) {
      const bf16x8 bf = *(const bf16x8*)(bp + i * 512);
      acc[i] = __builtin_amdgcn_mfma_f32_16x16x32_bf16(xf, bf, acc[i], 0, 0, 0);
    }
  }
  __syncthreads();  // all waves done with slabs -> reuse for reduction

  float* __restrict__ redp = (float*)smem;            // [8][7][4][64] = 57344 B
  float* __restrict__ sp   = (float*)(smem + 57344);  // [112] column partials
  if (w >= 8) {
#pragma unroll
    for (int i = 0; i < 7; ++i)
#pragma unroll
      for (int j = 0; j < 4; ++j)
        redp[((w - 8) * 7 + i) * 256 + j * 64 + lane] = acc[i][j];
  }
  if (t < NCP) sp[t] = 0.f;
  __syncthreads();
  if (w < 8) {
#pragma unroll
    for (int i = 0; i < 7; ++i)
#pragma unroll
      for (int j = 0; j < 4; ++j)
        redp[(w * 7 + i) * 256 + j * 64 + lane] += acc[i][j];
  }
  __syncthreads();

  // epilogue: waves 0..3 each own j = w (rows g*4 + j)
  if (w < 4) {
    const int j = w;
    float v[7];
#pragma unroll
    for (int i = 0; i < 7; ++i) {
      float s = 0.f;
#pragma unroll
      for (int w2 = 0; w2 < 8; ++w2)
        s += redp[(w2 * 7 + i) * 256 + j * 64 + lane];
      v[i] = s;
    }
    const bool v6  = (96 + r) < NC;
    const int  row = row0 + g * 4 + j;
    const int  yr  = Y[row];

    float m = -INFINITY;
#pragma unroll
    for (int i = 0; i < 6; ++i) m = fmaxf(m, v[i]);
    if (v6) m = fmaxf(m, v[6]);
#pragma unroll
    for (int off = 8; off > 0; off >>= 1) m = fmaxf(m, __shfl_xor(m, off));

    float e[7];
    float se = 0.f, py = 0.f;
#pragma unroll
    for (int i = 0; i < 7; ++i) {
      const bool valid = (i < 6) | v6;
      e[i] = valid ? __expf(v[i] - m) : 0.f;
      se += e[i];
      if (i * 16 + r == yr) py = v[i];
    }
#pragma unroll
    for (int off = 8; off > 0; off >>= 1) {
      se += __shfl_xor(se, off);
      py += __shfl_xor(py, off);
    }
    const float ce  = m + __logf(se) - py;
    const float inv = 1.f / se;

    const float* __restrict__ uty = Ut + yr * NC;
    float ap = 0.f;
    float s[7];
#pragma unroll
    for (int i = 0; i < 7; ++i) {
      const int col = i * 16 + r;
      s[i] = e[i] * inv - (col == yr ? 1.f : 0.f);
      const float u = ((i < 6) | v6) ? uty[col] : 0.f;
      ap = fmaf(s[i], u, ap);
    }
#pragma unroll
    for (int off = 8; off > 0; off >>= 1) ap += __shfl_xor(ap, off);

    if (r == 0) {
      rowce[row] = ce;   // plain stores, no global atomics
      rowap[row] = ap;
    }
#pragma unroll
    for (int i = 0; i < 7; ++i) atomicAdd(&sp[i * 16 + r], s[i]);
  }
  __syncthreads();
  if (t < NCP) S_part[(size_t)blockIdx.x * NCP + t] = sp[t];
}

// ---- final: hist(Y), reduce S_part/rowce/rowap, cls_ap, V[c] dot, loss -----
__global__ __launch_bounds__(1024) void k_final(const int* __restrict__ Y,
                                                const float* __restrict__ Ut,
                                                const float* __restrict__ S_part,
                                                const float* __restrict__ rowce,
                                                const float* __restrict__ rowap,
                                                float* __restrict__ out) {
  __shared__ int   hist[NC];
  __shared__ float stot[NCP];
  __shared__ float clsap[NC];
  __shared__ float red2[1024];
  const int t = threadIdx.x;
  if (t < NC) { hist[t] = 0; clsap[t] = 0.f; }
  if (t < NCP) stot[t] = 0.f;
  __syncthreads();

  {  // S_part reduction: c = t&127, 8 block-groups
    const int c  = t & 127;
    const int bg = t >> 7;
    if (c < NCP) {
      float s = 0.f;
      for (int b = bg; b < 512; b += 8) s += S_part[(size_t)b * NCP + c];
      atomicAdd(&stot[c], s);
    }
  }
  float cet = 0.f, apt = 0.f;
  for (int i = t; i < NB; i += 1024) {
    const float a = rowap[i];
    const int   y = Y[i];
    cet += rowce[i];
    apt += a;
    atomicAdd(&hist[y], 1);
    atomicAdd(&clsap[y], a);
  }
  red2[t] = cet;
  __syncthreads();
  for (int off = 512; off > 0; off >>= 1) {
    if (t < off) red2[t] += red2[t + off];
    __syncthreads();
  }
  const float cetot = red2[0];
  __syncthreads();
  red2[t] = apt;
  __syncthreads();
  for (int off = 512; off > 0; off >>= 1) {
    if (t < off) red2[t] += red2[t + off];
    __syncthreads();
  }
  const float aptot = red2[0];
  __syncthreads();

  float part = 0.f;
  if (t < NC) {
    float dot = 0.f;
    for (int r = 0; r < NC; ++r) dot = fmaf(stot[r], Ut[t * NC + r], dot);
    part = (float)hist[t] * (dot - clsap[t]);
  }
  red2[t] = part;
  __syncthreads();
  for (int off = 512; off > 0; off >>= 1) {
    if (t < off) red2[t] += red2[t + off];
    __syncthreads();
  }
  if (t == 0) {
    out[0] = (cetot + ALPHA_ * (red2[0] - aptot + (float)NB * MARGIN_)) /
             (float)NB;
  }
}

extern "C" void kernel_launch(void* const* d_in, const int* in_sizes, int n_in,
                              void* d_out, int out_size, void* d_ws,
                              size_t ws_size, hipStream_t stream) {
  const float* X = (const float*)d_in[0];
  const float* W = (const float*)d_in[1];
  const float* A = (const float*)d_in[2];
  const int*   Y = (const int*)d_in[3];
  float* out = (float*)d_out;
  char*  ws  = (char*)d_ws;

  float*          G2     = (float*)(ws + 0);       // 50176 B
  float*          pa2    = (float*)(ws + 50176);   // 50176 B
  float*          Ut     = (float*)(ws + 100352);  // 40000 B
  unsigned short* Wtf    = (unsigned short*)(ws + 147456);  // 458752 B
  float*          S_part = (float*)(ws + 606208);  // 512*112*4 = 229376 B
  float*          rowce  = (float*)(ws + 835584);  // 32768 B
  float*          rowap  = (float*)(ws + 868352);  // 32768 B

  k_prepW<<<112, 256, 0, stream>>>(W, Wtf);
  k_prepG<<<49, 512, 0, stream>>>(Wtf, A, G2, pa2);
  k_prep2<<<NC, 128, 0, stream>>>(G2, pa2, Ut);
  k_main<<<NB / 16, 1024, 0, stream>>>(X, Wtf, Y, Ut, S_part, rowce, rowap);
  k_final<<<1, 1024, 0, stream>>>(Y, Ut, S_part, rowce, rowap, out);
}

// Round 9
// 69.209 us; speedup vs baseline: 1.1498x; 1.1498x over previous
//
#include <hip/hip_runtime.h>
#include <math.h>

#define NB      8192
#define ND      2048
#define NC      100
#define NCP     112
#define NREP    32
#define ALPHA_  2.0f
#define MARGIN_ 0.05f

typedef short bf16x8 __attribute__((ext_vector_type(8)));
typedef float f32x4 __attribute__((ext_vector_type(4)));

static __device__ __forceinline__ unsigned short f2bf(float f) {
  unsigned u = __float_as_uint(f);
  u += 0x7FFFu + ((u >> 16) & 1u);
  return (unsigned short)(u >> 16);
}

// ---- prepW: Wtf fragment-major bf16: frag f=(ws*7+i)*64+l holds ------------
// W[ws*32+(l>>4)*8+j][i*16+(l&15)], j=0..7 (zero-pad col>=100)
__global__ __launch_bounds__(256) void k_prepW(const float* __restrict__ W,
                                               unsigned short* __restrict__ Wtf) {
  const int f   = blockIdx.x * 256 + threadIdx.x;  // 0..28671
  const int ws  = f / 448;
  const int rem = f - ws * 448;
  const int i   = rem >> 6;
  const int l   = rem & 63;
  const int col = i * 16 + (l & 15);
  const int k0  = ws * 32 + (l >> 4) * 8;
  bf16x8 v;
#pragma unroll
  for (int j = 0; j < 8; ++j)
    v[j] = (short)((col < NC) ? f2bf(W[(size_t)(k0 + j) * NC + col]) : 0);
  *(bf16x8*)(Wtf + (size_t)f * 8) = v;
}

// ---- prepG: G2 = W^T W, pa2 = A @ W (112x112 tiles via MFMA, no atomics) ---
__global__ __launch_bounds__(512) void k_prepG(const unsigned short* __restrict__ Wtf,
                                               const float* __restrict__ A,
                                               float* __restrict__ G2,
                                               float* __restrict__ pa2) {
  __shared__ float red[8][8][64];  // wave, val(4 G + 4 pa), lane
  const int t    = threadIdx.x;
  const int w    = t >> 6;
  const int lane = t & 63;
  const int ti   = blockIdx.x / 7;
  const int tj   = blockIdx.x % 7;
  const int arow = ti * 16 + (lane & 15);

  f32x4 accG = {0.f, 0.f, 0.f, 0.f};
  f32x4 accP = {0.f, 0.f, 0.f, 0.f};
#pragma unroll
  for (int s = 0; s < 8; ++s) {
    const int ws = w * 8 + s;
    const bf16x8 afr = *(const bf16x8*)(Wtf + (size_t)(ws * 7 + ti) * 512 + lane * 8);
    const bf16x8 bfr = *(const bf16x8*)(Wtf + (size_t)(ws * 7 + tj) * 512 + lane * 8);
    accG = __builtin_amdgcn_mfma_f32_16x16x32_bf16(afr, bfr, accG, 0, 0, 0);
    bf16x8 aa;
    if (arow < NC) {
      const float* __restrict__ ar =
          A + (size_t)arow * ND + ws * 32 + (lane >> 4) * 8;
      const float4 v0 = *(const float4*)(ar);
      const float4 v1 = *(const float4*)(ar + 4);
      aa[0] = (short)f2bf(v0.x); aa[1] = (short)f2bf(v0.y);
      aa[2] = (short)f2bf(v0.z); aa[3] = (short)f2bf(v0.w);
      aa[4] = (short)f2bf(v1.x); aa[5] = (short)f2bf(v1.y);
      aa[6] = (short)f2bf(v1.z); aa[7] = (short)f2bf(v1.w);
    } else {
#pragma unroll
      for (int q = 0; q < 8; ++q) aa[q] = 0;
    }
    accP = __builtin_amdgcn_mfma_f32_16x16x32_bf16(aa, bfr, accP, 0, 0, 0);
  }
#pragma unroll
  for (int rg = 0; rg < 4; ++rg) {
    red[w][rg][lane]     = accG[rg];
    red[w][4 + rg][lane] = accP[rg];
  }
  __syncthreads();
  if (w < 2) {
    const int vb = w * 4;  // 0: G, 4: pa
    float* __restrict__ dst = (w == 0) ? G2 : pa2;
#pragma unroll
    for (int rg = 0; rg < 4; ++rg) {
      float s = 0.f;
#pragma unroll
      for (int w2 = 0; w2 < 8; ++w2) s += red[w2][vb + rg][lane];
      const int row = ti * 16 + (lane >> 4) * 4 + rg;
      dst[row * NCP + tj * 16 + (lane & 15)] = s;
    }
  }
}

// ---- prep2: T=softmax(pa)-I ; Ut[cp][r] = (G T^T)[r][cp]; blk0 zeroes ACC --
__global__ __launch_bounds__(128) void k_prep2(const float* __restrict__ G2,
                                               const float* __restrict__ pa2,
                                               float* __restrict__ Ut,
                                               float* __restrict__ ACCf) {
  __shared__ float vals[128];
  __shared__ float tl[128];
  const int cp = blockIdx.x;
  const int t  = threadIdx.x;
  if (cp == 0) {
    for (int i = t; i < NREP * NCP + 128; i += 128) ACCf[i] = 0.f;
  }
  const float v = (t < NC) ? pa2[cp * NCP + t] : -INFINITY;
  vals[t] = v;
  __syncthreads();
  float m = -INFINITY;
  for (int c = 0; c < NC; ++c) m = fmaxf(m, vals[c]);
  float se = 0.f;
  for (int c = 0; c < NC; ++c) se += __expf(vals[c] - m);
  tl[t] = (t < NC) ? (__expf(v - m) / se - (t == cp ? 1.f : 0.f)) : 0.f;
  __syncthreads();
  if (t < NC) {
    float u = 0.f;
    for (int c = 0; c < NC; ++c) u = fmaf(G2[c * NCP + t], tl[c], u);
    Ut[cp * NC + t] = u;
  }
}

// ---- main: 16 waves x 128-K slices, per-wave LDS slab, replicated-atomic ---
__global__ __launch_bounds__(1024, 2) void k_main(const float* __restrict__ X,
                                                  const unsigned short* __restrict__ Wtf,
                                                  const int* __restrict__ Y,
                                                  const float* __restrict__ Ut,
                                                  float* __restrict__ S_rep,
                                                  float* __restrict__ cls_ap,
                                                  float* __restrict__ sums) {
  __shared__ __align__(16) char smem[65536];  // 16 x 4KB wave slabs; reused
  const int t    = threadIdx.x;
  const int w    = t >> 6;     // wave 0..15 = K-slice (128 K each)
  const int lane = t & 63;
  const int row0 = blockIdx.x * 16;
  char* __restrict__ wbase = smem + w * 4096;

  // ---- per-wave stage: 16 rows x 128 K, f32 -> bf16, XOR-swizzled [row][k] --
  {
    const int srow = lane >> 2;
    const int sc   = lane & 3;
    const float* __restrict__ xr =
        X + (size_t)(row0 + srow) * ND + w * 128 + sc * 8;
    const int wsz = (srow & 7) << 4;
#pragma unroll
    for (int j = 0; j < 4; ++j) {
      const float4 v0 = *(const float4*)(xr + j * 32);
      const float4 v1 = *(const float4*)(xr + j * 32 + 4);
      bf16x8 p;
      p[0] = (short)f2bf(v0.x); p[1] = (short)f2bf(v0.y);
      p[2] = (short)f2bf(v0.z); p[3] = (short)f2bf(v0.w);
      p[4] = (short)f2bf(v1.x); p[5] = (short)f2bf(v1.y);
      p[6] = (short)f2bf(v1.z); p[7] = (short)f2bf(v1.w);
      *(bf16x8*)(wbase + srow * 256 + ((sc * 16 + j * 64) ^ wsz)) = p;
    }
  }
  // no barrier: slab is wave-private (ds_write->ds_read ordered in-wave)

  const int r = lane & 15;
  const int g = lane >> 4;

  f32x4 acc[7];
  const f32x4 z = {0.f, 0.f, 0.f, 0.f};
#pragma unroll
  for (int i = 0; i < 7; ++i) acc[i] = z;

  const char* __restrict__ abase = wbase + r * 256;
  const int asz = (r & 7) << 4;
#pragma unroll
  for (int s = 0; s < 4; ++s) {
    const bf16x8 xf = *(const bf16x8*)(abase + ((s * 64 + g * 16) ^ asz));
    const unsigned short* __restrict__ bp =
        Wtf + (size_t)((w * 4 + s) * 7) * 512 + lane * 8;
#pragma unroll
    for (int i = 0; i < 7; ++i) {
      const bf16x8 bf = *(const bf16x8*)(bp + i * 512);
      acc[i] = __builtin_amdgcn_mfma_f32_16x16x32_bf16(xf, bf, acc[i], 0, 0, 0);
    }
  }
  __syncthreads();  // all waves done with slabs -> reuse for reduction

  float* __restrict__ redp = (float*)smem;            // [8][7][4][64] = 57344 B
  float* __restrict__ sp   = (float*)(smem + 57344);  // [112] + ce + ap
  if (w >= 8) {
#pragma unroll
    for (int i = 0; i < 7; ++i)
#pragma unroll
      for (int j = 0; j < 4; ++j)
        redp[((w - 8) * 7 + i) * 256 + j * 64 + lane] = acc[i][j];
  }
  if (t < NCP + 2) sp[t] = 0.f;
  __syncthreads();
  if (w < 8) {
#pragma unroll
    for (int i = 0; i < 7; ++i)
#pragma unroll
      for (int j = 0; j < 4; ++j)
        redp[(w * 7 + i) * 256 + j * 64 + lane] += acc[i][j];
  }
  __syncthreads();

  // epilogue: waves 0..3 each own j = w (rows g*4 + j)
  if (w < 4) {
    const int j = w;
    float v[7];
#pragma unroll
    for (int i = 0; i < 7; ++i) {
      float s = 0.f;
#pragma unroll
      for (int w2 = 0; w2 < 8; ++w2)
        s += redp[(w2 * 7 + i) * 256 + j * 64 + lane];
      v[i] = s;
    }
    const bool v6  = (96 + r) < NC;
    const int  row = row0 + g * 4 + j;
    const int  yr  = Y[row];

    float m = -INFINITY;
#pragma unroll
    for (int i = 0; i < 6; ++i) m = fmaxf(m, v[i]);
    if (v6) m = fmaxf(m, v[6]);
#pragma unroll
    for (int off = 8; off > 0; off >>= 1) m = fmaxf(m, __shfl_xor(m, off));

    float e[7];
    float se = 0.f, py = 0.f;
#pragma unroll
    for (int i = 0; i < 7; ++i) {
      const bool valid = (i < 6) | v6;
      e[i] = valid ? __expf(v[i] - m) : 0.f;
      se += e[i];
      if (i * 16 + r == yr) py = v[i];
    }
#pragma unroll
    for (int off = 8; off > 0; off >>= 1) {
      se += __shfl_xor(se, off);
      py += __shfl_xor(py, off);
    }
    const float ce  = m + __logf(se) - py;
    const float inv = 1.f / se;

    const float* __restrict__ uty = Ut + yr * NC;
    float ap = 0.f;
    float s[7];
#pragma unroll
    for (int i = 0; i < 7; ++i) {
      const int col = i * 16 + r;
      s[i] = e[i] * inv - (col == yr ? 1.f : 0.f);
      const float u = ((i < 6) | v6) ? uty[col] : 0.f;
      ap = fmaf(s[i], u, ap);
    }
#pragma unroll
    for (int off = 8; off > 0; off >>= 1) ap += __shfl_xor(ap, off);

    if (r == 0) {
      atomicAdd(&sp[NCP], ce);
      atomicAdd(&sp[NCP + 1], ap);
      atomicAdd(&cls_ap[yr], ap);   // 16 global atomics / block
    }
#pragma unroll
    for (int i = 0; i < 7; ++i) atomicAdd(&sp[i * 16 + r], s[i]);
  }
  __syncthreads();
  if (t < NCP) atomicAdd(&S_rep[(blockIdx.x & (NREP - 1)) * NCP + t], sp[t]);
  if (t == NCP) atomicAdd(&sums[0], sp[NCP]);
  if (t == NCP + 1) atomicAdd(&sums[1], sp[NCP + 1]);
}

// ---- final: hist(Y), sum S_rep, V[c] dot, loss -----------------------------
__global__ __launch_bounds__(1024) void k_final(const int* __restrict__ Y,
                                                const float* __restrict__ Ut,
                                                const float* __restrict__ ACCf,
                                                float* __restrict__ out) {
  __shared__ int   hist[NC];
  __shared__ float stot[NCP];
  __shared__ float red2[1024];
  const int t = threadIdx.x;
  if (t < NC) hist[t] = 0;
  __syncthreads();
  for (int i = t; i < NB; i += 1024) atomicAdd(&hist[Y[i]], 1);
  if (t < NCP) {
    float s = 0.f;
#pragma unroll
    for (int rep = 0; rep < NREP; ++rep) s += ACCf[rep * NCP + t];
    stot[t] = s;
  }
  __syncthreads();
  float part = 0.f;
  if (t < NC) {
    float dot = 0.f;
    for (int r = 0; r < NC; ++r) dot = fmaf(stot[r], Ut[t * NC + r], dot);
    part = (float)hist[t] * (dot - ACCf[NREP * NCP + t]);
  }
  red2[t] = part;
  __syncthreads();
  for (int off = 512; off > 0; off >>= 1) {
    if (t < off) red2[t] += red2[t + off];
    __syncthreads();
  }
  if (t == 0) {
    const float ce = ACCf[NREP * NCP + NC];
    const float ap = ACCf[NREP * NCP + NC + 1];
    out[0] = (ce + ALPHA_ * (red2[0] - ap + (float)NB * MARGIN_)) / (float)NB;
  }
}

extern "C" void kernel_launch(void* const* d_in, const int* in_sizes, int n_in,
                              void* d_out, int out_size, void* d_ws,
                              size_t ws_size, hipStream_t stream) {
  const float* X = (const float*)d_in[0];
  const float* W = (const float*)d_in[1];
  const float* A = (const float*)d_in[2];
  const int*   Y = (const int*)d_in[3];
  float* out = (float*)d_out;
  char*  ws  = (char*)d_ws;

  float*          G2   = (float*)(ws + 0);       // 50176 B
  float*          pa2  = (float*)(ws + 50176);   // 50176 B
  float*          Ut   = (float*)(ws + 100352);  // 40000 B
  float*          ACCf = (float*)(ws + 140800);  // NREP*112 S_rep, 100 cls_ap,
                                                 // 2 sums  (zeroed in prep2)
  unsigned short* Wtf  = (unsigned short*)(ws + 157696);  // 458752 B

  k_prepW<<<112, 256, 0, stream>>>(W, Wtf);
  k_prepG<<<49, 512, 0, stream>>>(Wtf, A, G2, pa2);
  k_prep2<<<NC, 128, 0, stream>>>(G2, pa2, Ut, ACCf);
  k_main<<<NB / 16, 1024, 0, stream>>>(X, Wtf, Y, Ut, ACCf,
                                       ACCf + NREP * NCP,
                                       ACCf + NREP * NCP + NC);
  k_final<<<1, 1024, 0, stream>>>(Y, Ut, ACCf, out);
}

// Round 10
// 68.805 us; speedup vs baseline: 1.1565x; 1.0059x over previous
//
#include <hip/hip_runtime.h>
#include <math.h>

#define NB      8192
#define ND      2048
#define NC      100
#define NCP     112
#define ALPHA_  2.0f
#define MARGIN_ 0.05f

typedef short bf16x8 __attribute__((ext_vector_type(8)));
typedef float f32x4 __attribute__((ext_vector_type(4)));

static __device__ __forceinline__ unsigned short f2bf(float f) {
  unsigned u = __float_as_uint(f);
  u += 0x7FFFu + ((u >> 16) & 1u);
  return (unsigned short)(u >> 16);
}

// ---- prepW: Wtf fragment-major bf16: frag f=(ws*7+i)*64+l holds ------------
// W[ws*32+(l>>4)*8+j][i*16+(l&15)], j=0..7 (zero-pad col>=100)
__global__ __launch_bounds__(256) void k_prepW(const float* __restrict__ W,
                                               unsigned short* __restrict__ Wtf) {
  const int f   = blockIdx.x * 256 + threadIdx.x;  // 0..28671
  const int ws  = f / 448;
  const int rem = f - ws * 448;
  const int i   = rem >> 6;
  const int l   = rem & 63;
  const int col = i * 16 + (l & 15);
  const int k0  = ws * 32 + (l >> 4) * 8;
  bf16x8 v;
#pragma unroll
  for (int j = 0; j < 8; ++j)
    v[j] = (short)((col < NC) ? f2bf(W[(size_t)(k0 + j) * NC + col]) : 0);
  *(bf16x8*)(Wtf + (size_t)f * 8) = v;
}

// ---- prepG: G2 = W^T W, pa2 = A @ W (112x112 tiles via MFMA, no atomics) ---
__global__ __launch_bounds__(512) void k_prepG(const unsigned short* __restrict__ Wtf,
                                               const float* __restrict__ A,
                                               float* __restrict__ G2,
                                               float* __restrict__ pa2) {
  __shared__ float red[8][8][64];  // wave, val(4 G + 4 pa), lane
  const int t    = threadIdx.x;
  const int w    = t >> 6;
  const int lane = t & 63;
  const int ti   = blockIdx.x / 7;
  const int tj   = blockIdx.x % 7;
  const int arow = ti * 16 + (lane & 15);

  f32x4 accG = {0.f, 0.f, 0.f, 0.f};
  f32x4 accP = {0.f, 0.f, 0.f, 0.f};
#pragma unroll
  for (int s = 0; s < 8; ++s) {
    const int ws = w * 8 + s;
    const bf16x8 afr = *(const bf16x8*)(Wtf + (size_t)(ws * 7 + ti) * 512 + lane * 8);
    const bf16x8 bfr = *(const bf16x8*)(Wtf + (size_t)(ws * 7 + tj) * 512 + lane * 8);
    accG = __builtin_amdgcn_mfma_f32_16x16x32_bf16(afr, bfr, accG, 0, 0, 0);
    bf16x8 aa;
    if (arow < NC) {
      const float* __restrict__ ar =
          A + (size_t)arow * ND + ws * 32 + (lane >> 4) * 8;
      const float4 v0 = *(const float4*)(ar);
      const float4 v1 = *(const float4*)(ar + 4);
      aa[0] = (short)f2bf(v0.x); aa[1] = (short)f2bf(v0.y);
      aa[2] = (short)f2bf(v0.z); aa[3] = (short)f2bf(v0.w);
      aa[4] = (short)f2bf(v1.x); aa[5] = (short)f2bf(v1.y);
      aa[6] = (short)f2bf(v1.z); aa[7] = (short)f2bf(v1.w);
    } else {
#pragma unroll
      for (int q = 0; q < 8; ++q) aa[q] = 0;
    }
    accP = __builtin_amdgcn_mfma_f32_16x16x32_bf16(aa, bfr, accP, 0, 0, 0);
  }
#pragma unroll
  for (int rg = 0; rg < 4; ++rg) {
    red[w][rg][lane]     = accG[rg];
    red[w][4 + rg][lane] = accP[rg];
  }
  __syncthreads();
  if (w < 2) {
    const int vb = w * 4;  // 0: G, 4: pa
    float* __restrict__ dst = (w == 0) ? G2 : pa2;
#pragma unroll
    for (int rg = 0; rg < 4; ++rg) {
      float s = 0.f;
#pragma unroll
      for (int w2 = 0; w2 < 8; ++w2) s += red[w2][vb + rg][lane];
      const int row = ti * 16 + (lane >> 4) * 4 + rg;
      dst[row * NCP + tj * 16 + (lane & 15)] = s;
    }
  }
}

// ---- prep2: T=softmax(pa)-I ; Ut[cp][r] = (G T^T)[r][cp]; blk0 zeroes ------
__global__ __launch_bounds__(128) void k_prep2(const float* __restrict__ G2,
                                               const float* __restrict__ pa2,
                                               float* __restrict__ Ut,
                                               float* __restrict__ cls_ap) {
  __shared__ float vals[128];
  __shared__ float tl[128];
  const int cp = blockIdx.x;
  const int t  = threadIdx.x;
  if (cp == 0) cls_ap[t] = 0.f;  // 128 floats
  const float v = (t < NC) ? pa2[cp * NCP + t] : -INFINITY;
  vals[t] = v;
  __syncthreads();
  float m = -INFINITY;
  for (int c = 0; c < NC; ++c) m = fmaxf(m, vals[c]);
  float se = 0.f;
  for (int c = 0; c < NC; ++c) se += __expf(vals[c] - m);
  tl[t] = (t < NC) ? (__expf(v - m) / se - (t == cp ? 1.f : 0.f)) : 0.f;
  __syncthreads();
  if (t < NC) {
    float u = 0.f;
    for (int c = 0; c < NC; ++c) u = fmaf(G2[c * NCP + t], tl[c], u);
    Ut[cp * NC + t] = u;
  }
}

// ---- main: 8 waves x 256-K slices, explicit B double-buffer, store tail ----
__global__ __launch_bounds__(512, 4) void k_main(const float* __restrict__ X,
                                                 const unsigned short* __restrict__ Wtf,
                                                 const int* __restrict__ Y,
                                                 const float* __restrict__ Ut,
                                                 float* __restrict__ S_part,
                                                 float* __restrict__ rowce,
                                                 float* __restrict__ rowap) {
  __shared__ __align__(16) char smem[65536];  // 8 x 8KB wave slabs; reused
  const int t    = threadIdx.x;
  const int w    = t >> 6;     // wave 0..7 = K-slice (256 K each)
  const int lane = t & 63;
  const int row0 = blockIdx.x * 16;
  char* __restrict__ wbase = smem + w * 8192;

  // issue first B-fragment batch BEFORE the X stage (independent of LDS)
  const unsigned short* __restrict__ bp0 =
      Wtf + (size_t)(w * 8 * 7) * 512 + lane * 8;
  bf16x8 cur[7], nxt[7];
#pragma unroll
  for (int i = 0; i < 7; ++i) cur[i] = *(const bf16x8*)(bp0 + i * 512);

  // ---- per-wave stage: 16 rows x 256 K, f32 -> bf16, XOR-swizzled [row][k] --
  {
    const int srow = lane >> 2;
    const int sc   = lane & 3;
    const float* __restrict__ xr =
        X + (size_t)(row0 + srow) * ND + w * 256 + sc * 8;
    const int wsz = (srow & 7) << 4;
#pragma unroll
    for (int j = 0; j < 8; ++j) {
      const float4 v0 = *(const float4*)(xr + j * 32);
      const float4 v1 = *(const float4*)(xr + j * 32 + 4);
      bf16x8 p;
      p[0] = (short)f2bf(v0.x); p[1] = (short)f2bf(v0.y);
      p[2] = (short)f2bf(v0.z); p[3] = (short)f2bf(v0.w);
      p[4] = (short)f2bf(v1.x); p[5] = (short)f2bf(v1.y);
      p[6] = (short)f2bf(v1.z); p[7] = (short)f2bf(v1.w);
      *(bf16x8*)(wbase + srow * 512 + ((sc * 16 + j * 64) ^ wsz)) = p;
    }
  }
  // no barrier: slab is wave-private (ds_write->ds_read ordered in-wave)

  const int r = lane & 15;
  const int g = lane >> 4;

  f32x4 acc[7];
  const f32x4 z = {0.f, 0.f, 0.f, 0.f};
#pragma unroll
  for (int i = 0; i < 7; ++i) acc[i] = z;

  const char* __restrict__ abase = wbase + r * 512;
  const int asz = (r & 7) << 4;
#pragma unroll
  for (int s = 0; s < 8; ++s) {
    const bf16x8 xf = *(const bf16x8*)(abase + ((s * 64 + g * 16) ^ asz));
    if (s < 7) {
      const unsigned short* __restrict__ bpn = bp0 + (size_t)(s + 1) * 7 * 512;
#pragma unroll
      for (int i = 0; i < 7; ++i) nxt[i] = *(const bf16x8*)(bpn + i * 512);
    }
#pragma unroll
    for (int i = 0; i < 7; ++i)
      acc[i] = __builtin_amdgcn_mfma_f32_16x16x32_bf16(xf, cur[i], acc[i], 0, 0, 0);
#pragma unroll
    for (int i = 0; i < 7; ++i) cur[i] = nxt[i];
  }
  __syncthreads();  // all waves done with slabs -> reuse for reduction

  float* __restrict__ redp = (float*)smem;            // [8][7][4][64] = 57344 B
  float* __restrict__ sp   = (float*)(smem + 57344);  // [112] column partials
#pragma unroll
  for (int i = 0; i < 7; ++i)
#pragma unroll
    for (int j = 0; j < 4; ++j)
      redp[(w * 7 + i) * 256 + j * 64 + lane] = acc[i][j];
  if (t < NCP) sp[t] = 0.f;
  __syncthreads();

  // epilogue: waves 0..3 each own j = w (rows g*4 + j)
  if (w < 4) {
    const int j = w;
    float v[7];
#pragma unroll
    for (int i = 0; i < 7; ++i) {
      float s = 0.f;
#pragma unroll
      for (int w2 = 0; w2 < 8; ++w2)
        s += redp[(w2 * 7 + i) * 256 + j * 64 + lane];
      v[i] = s;
    }
    const bool v6  = (96 + r) < NC;
    const int  row = row0 + g * 4 + j;
    const int  yr  = Y[row];

    float m = -INFINITY;
#pragma unroll
    for (int i = 0; i < 6; ++i) m = fmaxf(m, v[i]);
    if (v6) m = fmaxf(m, v[6]);
#pragma unroll
    for (int off = 8; off > 0; off >>= 1) m = fmaxf(m, __shfl_xor(m, off));

    float e[7];
    float se = 0.f, py = 0.f;
#pragma unroll
    for (int i = 0; i < 7; ++i) {
      const bool valid = (i < 6) | v6;
      e[i] = valid ? __expf(v[i] - m) : 0.f;
      se += e[i];
      if (i * 16 + r == yr) py = v[i];
    }
#pragma unroll
    for (int off = 8; off > 0; off >>= 1) {
      se += __shfl_xor(se, off);
      py += __shfl_xor(py, off);
    }
    const float ce  = m + __logf(se) - py;
    const float inv = 1.f / se;

    const float* __restrict__ uty = Ut + yr * NC;
    float ap = 0.f;
    float s[7];
#pragma unroll
    for (int i = 0; i < 7; ++i) {
      const int col = i * 16 + r;
      s[i] = e[i] * inv - (col == yr ? 1.f : 0.f);
      const float u = ((i < 6) | v6) ? uty[col] : 0.f;
      ap = fmaf(s[i], u, ap);
    }
#pragma unroll
    for (int off = 8; off > 0; off >>= 1) ap += __shfl_xor(ap, off);

    if (r == 0) {
      rowce[row] = ce;   // plain stores, no global atomics
      rowap[row] = ap;
    }
#pragma unroll
    for (int i = 0; i < 7; ++i) atomicAdd(&sp[i * 16 + r], s[i]);
  }
  __syncthreads();
  if (t < NCP) S_part[(size_t)t * 512 + blockIdx.x] = sp[t];  // column-major
}

// ---- red: blocks 0..111 S columns; 112/113 ce/ap sums; 114..117 cls_ap -----
__global__ __launch_bounds__(256) void k_red(const int* __restrict__ Y,
                                             const float* __restrict__ S_part,
                                             const float* __restrict__ rowce,
                                             const float* __restrict__ rowap,
                                             float* __restrict__ stot,
                                             float* __restrict__ sums,
                                             float* __restrict__ cls_ap) {
  __shared__ float red[256];
  const int bid = blockIdx.x;
  const int t   = threadIdx.x;
  if (bid < NCP) {
    float s = S_part[(size_t)bid * 512 + t] + S_part[(size_t)bid * 512 + 256 + t];
    red[t] = s;
    __syncthreads();
    for (int off = 128; off > 0; off >>= 1) {
      if (t < off) red[t] += red[t + off];
      __syncthreads();
    }
    if (t == 0) stot[bid] = red[0];
  } else if (bid < 114) {
    const float* __restrict__ src = (bid == 112) ? rowce : rowap;
    float s = 0.f;
    for (int i = t; i < NB; i += 256) s += src[i];
    red[t] = s;
    __syncthreads();
    for (int off = 128; off > 0; off >>= 1) {
      if (t < off) red[t] += red[t + off];
      __syncthreads();
    }
    if (t == 0) sums[bid - 112] = red[0];
  } else {
    const int base = (bid - 114) * 2048;
#pragma unroll
    for (int q = 0; q < 8; ++q) {
      const int i = base + q * 256 + t;
      atomicAdd(&cls_ap[Y[i]], rowap[i]);
    }
  }
}

// ---- final: hist(Y), V[c] dot, loss ----------------------------------------
__global__ __launch_bounds__(256) void k_final(const int* __restrict__ Y,
                                               const float* __restrict__ Ut,
                                               const float* __restrict__ stot,
                                               const float* __restrict__ sums,
                                               const float* __restrict__ cls_ap,
                                               float* __restrict__ out) {
  __shared__ int   hist[NC];
  __shared__ float st[NC];
  __shared__ float red2[256];
  const int t = threadIdx.x;
  if (t < NC) { hist[t] = 0; st[t] = stot[t]; }
  __syncthreads();
  for (int i = t; i < NB; i += 256) atomicAdd(&hist[Y[i]], 1);
  __syncthreads();
  float part = 0.f;
  if (t < NC) {
    float dot = 0.f;
    for (int r = 0; r < NC; ++r) dot = fmaf(st[r], Ut[t * NC + r], dot);
    part = (float)hist[t] * (dot - cls_ap[t]);
  }
  red2[t] = part;
  __syncthreads();
  for (int off = 128; off > 0; off >>= 1) {
    if (t < off) red2[t] += red2[t + off];
    __syncthreads();
  }
  if (t == 0) {
    out[0] = (sums[0] + ALPHA_ * (red2[0] - sums[1] + (float)NB * MARGIN_)) /
             (float)NB;
  }
}

extern "C" void kernel_launch(void* const* d_in, const int* in_sizes, int n_in,
                              void* d_out, int out_size, void* d_ws,
                              size_t ws_size, hipStream_t stream) {
  const float* X = (const float*)d_in[0];
  const float* W = (const float*)d_in[1];
  const float* A = (const float*)d_in[2];
  const int*   Y = (const int*)d_in[3];
  float* out = (float*)d_out;
  char*  ws  = (char*)d_ws;

  float*          G2     = (float*)(ws + 0);       // 50176 B
  float*          pa2    = (float*)(ws + 50176);   // 50176 B
  float*          Ut     = (float*)(ws + 100352);  // 40000 B
  float*          cls_ap = (float*)(ws + 140800);  // 512 B (zeroed in prep2)
  float*          stot   = (float*)(ws + 141312);  // 448 B
  float*          sums   = (float*)(ws + 141824);  // 8 B
  unsigned short* Wtf    = (unsigned short*)(ws + 147456);  // 458752 B
  float*          S_part = (float*)(ws + 606208);  // 112*512*4 = 229376 B
  float*          rowce  = (float*)(ws + 835584);  // 32768 B
  float*          rowap  = (float*)(ws + 868352);  // 32768 B

  k_prepW<<<112, 256, 0, stream>>>(W, Wtf);
  k_prepG<<<49, 512, 0, stream>>>(Wtf, A, G2, pa2);
  k_prep2<<<NC, 128, 0, stream>>>(G2, pa2, Ut, cls_ap);
  k_main<<<NB / 16, 512, 0, stream>>>(X, Wtf, Y, Ut, S_part, rowce, rowap);
  k_red<<<118, 256, 0, stream>>>(Y, S_part, rowce, rowap, stot, sums, cls_ap);
  k_final<<<1, 256, 0, stream>>>(Y, Ut, stot, sums, cls_ap, out);
}